// Round 3
// baseline (760.937 us; speedup 1.0000x reference)
//
#include <hip/hip_runtime.h>
#include <cstdint>
#include <cstddef>

#define B_   8
#define S_   2048
#define H_   1024
#define K3_  3072              // 3*H
#define SC_  512               // time-chunk length
#define MC_  (B_ * SC_)        // 4096 rows per GEMM chunk
#define NCH_ (S_ / SC_)        // 4 chunks
#define WSCALE 32.0f           // pre-scale W so f16 lo-plane stays normal-range

typedef __attribute__((ext_vector_type(8))) _Float16 f16x8;
typedef __attribute__((ext_vector_type(4))) _Float16 f16x4;
typedef __attribute__((ext_vector_type(4))) float f32x4;

// --------------------------------------------- cast x time-slice -> f16 hi/lo (chunk-local rows)
// chunk row r in [0,4096): b = r>>9, s = s0 + (r&511); source row in x = b*S_ + s
__global__ __launch_bounds__(256) void castx_kernel(const float4* __restrict__ X,
                                                    f16x4* __restrict__ Xh,
                                                    f16x4* __restrict__ Xl, int s0) {
    int i = blockIdx.x * 256 + threadIdx.x;        // float4 index in chunk, [0, 4096*256)
    int r  = i >> 8;                               // chunk row
    int c4 = i & 255;                              // float4 within row
    int b  = r >> 9;
    int sl = r & (SC_ - 1);
    size_t src = ((size_t)b * S_ + s0 + sl) * (H_ / 4) + c4;
    float4 v = ((const float4*)X)[src];
    _Float16 h0 = (_Float16)v.x, h1 = (_Float16)v.y, h2 = (_Float16)v.z, h3 = (_Float16)v.w;
    f16x4 hv = {h0, h1, h2, h3};
    f16x4 lv = {(_Float16)(v.x - (float)h0), (_Float16)(v.y - (float)h1),
                (_Float16)(v.z - (float)h2), (_Float16)(v.w - (float)h3)};
    Xh[i] = hv;
    Xl[i] = lv;
}

// ------------------------- transpose + scale + split W [H,3H] fp32 -> Wt hi/lo [3H,H] f16
__global__ __launch_bounds__(256) void transW_kernel(const float* __restrict__ W,
                                                     _Float16* __restrict__ Wth,
                                                     _Float16* __restrict__ Wtl) {
    __shared__ float tile[32][33];
    int bc  = blockIdx.x * 32;         // col block in W (N dim)
    int brr = blockIdx.y * 32;         // row block in W (K dim)
    int tx = threadIdx.x & 31;
    int ty = threadIdx.x >> 5;         // 0..7
#pragma unroll
    for (int i = 0; i < 4; ++i) {
        int r = ty + i * 8;
        tile[r][tx] = W[(size_t)(brr + r) * K3_ + bc + tx];
    }
    __syncthreads();
#pragma unroll
    for (int i = 0; i < 4; ++i) {
        int r = ty + i * 8;            // row in Wt tile = col in W
        float v = tile[tx][r] * WSCALE;
        _Float16 h = (_Float16)v;
        _Float16 l = (_Float16)(v - (float)h);
        Wth[(size_t)(bc + r) * H_ + brr + tx] = h;
        Wtl[(size_t)(bc + r) * H_ + brr + tx] = l;
    }
}

// ---------------------------------------------------------------- split-f16 MFMA GEMM (one chunk)
// U[m,n] = (1/WSCALE) * sum_k (Ah+Al)[m,k]*(Bh+Bl)[n,k], 3-term: AhBh + AhBl + AlBh
// A* [4096,1024] f16 chunk-local, B* [3072,1024] f16. Output U fp32 [4096,3072].
__global__ __launch_bounds__(256) void gemm_kernel(const _Float16* __restrict__ Ah,
                                                   const _Float16* __restrict__ Al,
                                                   const _Float16* __restrict__ Bh,
                                                   const _Float16* __restrict__ Bl,
                                                   float* __restrict__ C) {
    __shared__ _Float16 Ahs[128 * 32];
    __shared__ _Float16 Als[128 * 32];
    __shared__ _Float16 Bhs[128 * 32];
    __shared__ _Float16 Bls[128 * 32];
    const int tid  = threadIdx.x;
    const int lane = tid & 63;
    const int w    = tid >> 6;
    const int wm   = (w >> 1) * 64;
    const int wn   = (w & 1) * 64;
    const int bm   = blockIdx.y * 128;
    const int bn   = blockIdx.x * 128;
    const int K    = 1024;

    f32x4 acc[4][4];
#pragma unroll
    for (int i = 0; i < 4; ++i)
#pragma unroll
        for (int j = 0; j < 4; ++j) {
            f32x4 z = {0.f, 0.f, 0.f, 0.f};
            acc[i][j] = z;
        }

    const int quad = lane >> 4;
    const int lrow = lane & 15;

    for (int kk = 0; kk < K; kk += 32) {
#pragma unroll
        for (int j = 0; j < 2; ++j) {
            int idx = j * 256 + tid;          // 0..511
            int row = idx >> 2;               // 4 lanes per 32-elem row
            int kp  = (idx & 3) << 3;
            size_t aoff = (size_t)(bm + row) * K + kk + kp;
            size_t boff = (size_t)(bn + row) * K + kk + kp;
            unsigned base = (unsigned)(j * 256 + (tid & ~63)) * 16u;  // wave-uniform bytes
            __builtin_amdgcn_global_load_lds(
                (const __attribute__((address_space(1))) void*)(Ah + aoff),
                (__attribute__((address_space(3))) void*)((char*)Ahs + base), 16, 0, 0);
            __builtin_amdgcn_global_load_lds(
                (const __attribute__((address_space(1))) void*)(Al + aoff),
                (__attribute__((address_space(3))) void*)((char*)Als + base), 16, 0, 0);
            __builtin_amdgcn_global_load_lds(
                (const __attribute__((address_space(1))) void*)(Bh + boff),
                (__attribute__((address_space(3))) void*)((char*)Bhs + base), 16, 0, 0);
            __builtin_amdgcn_global_load_lds(
                (const __attribute__((address_space(1))) void*)(Bl + boff),
                (__attribute__((address_space(3))) void*)((char*)Bls + base), 16, 0, 0);
        }
        __syncthreads();

        f16x8 ah[4], al[4], bh[4], bl[4];
#pragma unroll
        for (int i = 0; i < 4; ++i) {
            ah[i] = *(const f16x8*)(Ahs + (wm + i * 16 + lrow) * 32 + quad * 8);
            al[i] = *(const f16x8*)(Als + (wm + i * 16 + lrow) * 32 + quad * 8);
        }
#pragma unroll
        for (int j = 0; j < 4; ++j) {
            bh[j] = *(const f16x8*)(Bhs + (wn + j * 16 + lrow) * 32 + quad * 8);
            bl[j] = *(const f16x8*)(Bls + (wn + j * 16 + lrow) * 32 + quad * 8);
        }

#pragma unroll
        for (int i = 0; i < 4; ++i)
#pragma unroll
            for (int j = 0; j < 4; ++j) {
                acc[i][j] = __builtin_amdgcn_mfma_f32_16x16x32_f16(al[i], bh[j], acc[i][j], 0, 0, 0);
                acc[i][j] = __builtin_amdgcn_mfma_f32_16x16x32_f16(ah[i], bl[j], acc[i][j], 0, 0, 0);
                acc[i][j] = __builtin_amdgcn_mfma_f32_16x16x32_f16(ah[i], bh[j], acc[i][j], 0, 0, 0);
            }
        __syncthreads();
    }

    // epilogue: C/D layout col = lane&15, row = (lane>>4)*4 + r ; undo W pre-scale
    const float inv = 1.0f / WSCALE;
#pragma unroll
    for (int i = 0; i < 4; ++i)
#pragma unroll
        for (int j = 0; j < 4; ++j)
#pragma unroll
            for (int r = 0; r < 4; ++r) {
                int row = bm + wm + i * 16 + quad * 4 + r;
                int col = bn + wn + j * 16 + lrow;
                C[(size_t)row * K3_ + col] = acc[i][j][r] * inv;
            }
}

// ---------------------------------------------------------------- sequential scan (one chunk)
__global__ __launch_bounds__(64) void scan_kernel(const float* __restrict__ U,
                                                  const float* __restrict__ X,
                                                  const float* __restrict__ vf,
                                                  const float* __restrict__ vr,
                                                  const float* __restrict__ bfv,
                                                  const float* __restrict__ brv,
                                                  float* __restrict__ Y,
                                                  float* __restrict__ Cf,
                                                  float* __restrict__ carry,
                                                  int s0, int last) {
    int gid = blockIdx.x * 64 + threadIdx.x;   // 0..8191
    int b = gid >> 10;
    int h = gid & 1023;
    float vfh = vf[h], vrh = vr[h], bfh = bfv[h], brh = brv[h];
    const float* Ub = U + (size_t)b * SC_ * K3_ + h;            // chunk-local rows
    const float* Xb = X + ((size_t)b * S_ + s0) * H_ + h;
    float* Yb = Y + ((size_t)b * S_ + s0) * H_ + h;
    float c = (s0 == 0) ? 0.f : carry[gid];

    float Af[8], Ac[8], Ar[8], Ax[8];
    float Bf[8], Bc[8], Br[8], Bx[8];

    auto LOAD = [&](int t0, float (&sf)[8], float (&sc)[8], float (&sr)[8], float (&sx)[8]) {
#pragma unroll
        for (int u = 0; u < 8; ++u) {
            size_t o = (size_t)(t0 + u) * K3_;
            sf[u] = Ub[o];
            sc[u] = Ub[o + H_];
            sr[u] = Ub[o + 2 * H_];
            sx[u] = Xb[(size_t)(t0 + u) * H_];
        }
    };
    auto COMP = [&](int t0, float (&sf)[8], float (&sc)[8], float (&sr)[8], float (&sx)[8]) {
#pragma unroll
        for (int u = 0; u < 8; ++u) {
            float zf = sf[u] + bfh + vfh * c;
            float zr = sr[u] + brh + vrh * c;
            float xc = sc[u];
            float ft = 1.f / (1.f + __expf(-zf));
            float rt = 1.f / (1.f + __expf(-zr));
            c = ft * (c - xc) + xc;
            float xv = sx[u];
            float ht = rt * (c - xv) + xv;
            Yb[(size_t)(t0 + u) * H_] = ht;
        }
    };

    LOAD(0, Af, Ac, Ar, Ax);
    for (int t0 = 0; t0 < SC_; t0 += 16) {
        LOAD(t0 + 8, Bf, Bc, Br, Bx);
        COMP(t0, Af, Ac, Ar, Ax);
        if (t0 + 16 < SC_) LOAD(t0 + 16, Af, Ac, Ar, Ax);
        COMP(t0 + 8, Bf, Bc, Br, Bx);
    }
    carry[gid] = c;
    if (last) Cf[(size_t)b * H_ + h] = c;
}

// ---------------------------------------------------------------- launcher
extern "C" void kernel_launch(void* const* d_in, const int* in_sizes, int n_in,
                              void* d_out, int out_size, void* d_ws, size_t ws_size,
                              hipStream_t stream) {
    const float* x  = (const float*)d_in[0];
    const float* W  = (const float*)d_in[1];
    const float* vf = (const float*)d_in[2];
    const float* vr = (const float*)d_in[3];
    const float* bf = (const float*)d_in[4];
    const float* br = (const float*)d_in[5];
    float* y  = (float*)d_out;
    float* cf = y + (size_t)B_ * S_ * H_;

    // ws layout (bytes): U_c fp32 50.3MB | xh 8.4MB | xl 8.4MB | Wth 6.3MB | Wtl 6.3MB | carry 32KB
    // total ~79.8MB  (R1's 140.5MB layout is the proven upper bound)
    float* U = (float*)d_ws;
    _Float16* xh  = (_Float16*)(U + (size_t)MC_ * K3_);
    _Float16* xl  = xh + (size_t)MC_ * H_;
    _Float16* Wth = xl + (size_t)MC_ * H_;
    _Float16* Wtl = Wth + (size_t)K3_ * H_;
    float* carry  = (float*)(Wtl + (size_t)K3_ * H_);

    transW_kernel<<<dim3(K3_ / 32, H_ / 32), 256, 0, stream>>>(W, Wth, Wtl);
    for (int ci = 0; ci < NCH_; ++ci) {
        int s0 = ci * SC_;
        castx_kernel<<<(MC_ * H_ / 4) / 256, 256, 0, stream>>>((const float4*)x, (f16x4*)xh, (f16x4*)xl, s0);
        gemm_kernel<<<dim3(K3_ / 128, MC_ / 128), 256, 0, stream>>>(xh, xl, Wth, Wtl, U);
        scan_kernel<<<(B_ * H_) / 64, 64, 0, stream>>>(U, x, vf, vr, bf, br, y, cf, carry,
                                                       s0, ci == NCH_ - 1 ? 1 : 0);
    }
}

// Round 4
// 693.128 us; speedup vs baseline: 1.0978x; 1.0978x over previous
//
#include <hip/hip_runtime.h>
#include <cstdint>
#include <cstddef>

#define B_   8
#define S_   2048
#define H_   1024
#define K3_  3072              // 3*H
#define SC_  512               // time-chunk length
#define MC_  (B_ * SC_)        // 4096 rows per GEMM chunk
#define NCH_ (S_ / SC_)        // 4 chunks
#define WSCALE 32.0f           // pre-scale W so f16 lo-plane stays normal-range

typedef __attribute__((ext_vector_type(8))) _Float16 f16x8;
typedef __attribute__((ext_vector_type(4))) _Float16 f16x4;
typedef __attribute__((ext_vector_type(4))) float f32x4;

// --------------------------------------------- cast x time-slice -> f16 hi/lo (chunk-local rows)
__global__ __launch_bounds__(256) void castx_kernel(const float4* __restrict__ X,
                                                    f16x4* __restrict__ Xh,
                                                    f16x4* __restrict__ Xl, int s0) {
    int i = blockIdx.x * 256 + threadIdx.x;        // float4 index in chunk, [0, 4096*256)
    int r  = i >> 8;                               // chunk row
    int c4 = i & 255;                              // float4 within row
    int b  = r >> 9;
    int sl = r & (SC_ - 1);
    size_t src = ((size_t)b * S_ + s0 + sl) * (H_ / 4) + c4;
    float4 v = ((const float4*)X)[src];
    _Float16 h0 = (_Float16)v.x, h1 = (_Float16)v.y, h2 = (_Float16)v.z, h3 = (_Float16)v.w;
    f16x4 hv = {h0, h1, h2, h3};
    f16x4 lv = {(_Float16)(v.x - (float)h0), (_Float16)(v.y - (float)h1),
                (_Float16)(v.z - (float)h2), (_Float16)(v.w - (float)h3)};
    Xh[i] = hv;
    Xl[i] = lv;
}

// ------------------------- transpose + scale + split W [H,3H] fp32 -> Wt hi/lo [3H,H] f16
__global__ __launch_bounds__(256) void transW_kernel(const float* __restrict__ W,
                                                     _Float16* __restrict__ Wth,
                                                     _Float16* __restrict__ Wtl) {
    __shared__ float tile[32][33];
    int bc  = blockIdx.x * 32;
    int brr = blockIdx.y * 32;
    int tx = threadIdx.x & 31;
    int ty = threadIdx.x >> 5;
#pragma unroll
    for (int i = 0; i < 4; ++i) {
        int r = ty + i * 8;
        tile[r][tx] = W[(size_t)(brr + r) * K3_ + bc + tx];
    }
    __syncthreads();
#pragma unroll
    for (int i = 0; i < 4; ++i) {
        int r = ty + i * 8;            // row in Wt tile = col in W
        float v = tile[tx][r] * WSCALE;
        _Float16 h = (_Float16)v;
        _Float16 l = (_Float16)(v - (float)h);
        Wth[(size_t)(bc + r) * H_ + brr + tx] = h;
        Wtl[(size_t)(bc + r) * H_ + brr + tx] = l;
    }
}

// ---------------------------------------------------------------- split-f16 MFMA GEMM (one chunk)
// U[m,n] = (1/WSCALE) * sum_k (Ah+Al)[m,k]*(Bh+Bl)[n,k], 3-term: AhBh + AhBl + AlBh
__global__ __launch_bounds__(256) void gemm_kernel(const _Float16* __restrict__ Ah,
                                                   const _Float16* __restrict__ Al,
                                                   const _Float16* __restrict__ Bh,
                                                   const _Float16* __restrict__ Bl,
                                                   float* __restrict__ C) {
    __shared__ _Float16 Ahs[128 * 32];
    __shared__ _Float16 Als[128 * 32];
    __shared__ _Float16 Bhs[128 * 32];
    __shared__ _Float16 Bls[128 * 32];
    const int tid  = threadIdx.x;
    const int lane = tid & 63;
    const int w    = tid >> 6;
    const int wm   = (w >> 1) * 64;
    const int wn   = (w & 1) * 64;
    const int bm   = blockIdx.y * 128;
    const int bn   = blockIdx.x * 128;
    const int K    = 1024;

    f32x4 acc[4][4];
#pragma unroll
    for (int i = 0; i < 4; ++i)
#pragma unroll
        for (int j = 0; j < 4; ++j) {
            f32x4 z = {0.f, 0.f, 0.f, 0.f};
            acc[i][j] = z;
        }

    const int quad = lane >> 4;
    const int lrow = lane & 15;

    for (int kk = 0; kk < K; kk += 32) {
#pragma unroll
        for (int j = 0; j < 2; ++j) {
            int idx = j * 256 + tid;          // 0..511
            int row = idx >> 2;
            int kp  = (idx & 3) << 3;
            size_t aoff = (size_t)(bm + row) * K + kk + kp;
            size_t boff = (size_t)(bn + row) * K + kk + kp;
            unsigned base = (unsigned)(j * 256 + (tid & ~63)) * 16u;  // wave-uniform bytes
            __builtin_amdgcn_global_load_lds(
                (const __attribute__((address_space(1))) void*)(Ah + aoff),
                (__attribute__((address_space(3))) void*)((char*)Ahs + base), 16, 0, 0);
            __builtin_amdgcn_global_load_lds(
                (const __attribute__((address_space(1))) void*)(Al + aoff),
                (__attribute__((address_space(3))) void*)((char*)Als + base), 16, 0, 0);
            __builtin_amdgcn_global_load_lds(
                (const __attribute__((address_space(1))) void*)(Bh + boff),
                (__attribute__((address_space(3))) void*)((char*)Bhs + base), 16, 0, 0);
            __builtin_amdgcn_global_load_lds(
                (const __attribute__((address_space(1))) void*)(Bl + boff),
                (__attribute__((address_space(3))) void*)((char*)Bls + base), 16, 0, 0);
        }
        __syncthreads();

        f16x8 ah[4], al[4], bh[4], bl[4];
#pragma unroll
        for (int i = 0; i < 4; ++i) {
            ah[i] = *(const f16x8*)(Ahs + (wm + i * 16 + lrow) * 32 + quad * 8);
            al[i] = *(const f16x8*)(Als + (wm + i * 16 + lrow) * 32 + quad * 8);
        }
#pragma unroll
        for (int j = 0; j < 4; ++j) {
            bh[j] = *(const f16x8*)(Bhs + (wn + j * 16 + lrow) * 32 + quad * 8);
            bl[j] = *(const f16x8*)(Bls + (wn + j * 16 + lrow) * 32 + quad * 8);
        }

#pragma unroll
        for (int i = 0; i < 4; ++i)
#pragma unroll
            for (int j = 0; j < 4; ++j) {
                acc[i][j] = __builtin_amdgcn_mfma_f32_16x16x32_f16(al[i], bh[j], acc[i][j], 0, 0, 0);
                acc[i][j] = __builtin_amdgcn_mfma_f32_16x16x32_f16(ah[i], bl[j], acc[i][j], 0, 0, 0);
                acc[i][j] = __builtin_amdgcn_mfma_f32_16x16x32_f16(ah[i], bh[j], acc[i][j], 0, 0, 0);
            }
        __syncthreads();
    }

    const float inv = 1.0f / WSCALE;
#pragma unroll
    for (int i = 0; i < 4; ++i)
#pragma unroll
        for (int j = 0; j < 4; ++j)
#pragma unroll
            for (int r = 0; r < 4; ++r) {
                int row = bm + wm + i * 16 + quad * 4 + r;
                int col = bn + wn + j * 16 + lrow;
                C[(size_t)row * K3_ + col] = acc[i][j][r] * inv;
            }
}

// ---------------------------------------------------------------- sequential scan (one chunk)
// 4 rolling 8-step register buffers -> up to 24 steps (384 B/lane, ~3 MB total) in flight.
__global__ __launch_bounds__(64, 1) void scan_kernel(const float* __restrict__ U,
                                                     const float* __restrict__ X,
                                                     const float* __restrict__ vf,
                                                     const float* __restrict__ vr,
                                                     const float* __restrict__ bfv,
                                                     const float* __restrict__ brv,
                                                     float* __restrict__ Y,
                                                     float* __restrict__ Cf,
                                                     float* __restrict__ carry,
                                                     int s0, int last) {
    int gid = blockIdx.x * 64 + threadIdx.x;   // 0..8191
    int b = gid >> 10;
    int h = gid & 1023;
    float vfh = vf[h], vrh = vr[h], bfh = bfv[h], brh = brv[h];
    const float* Ub = U + (size_t)b * SC_ * K3_ + h;            // chunk-local rows
    const float* Xb = X + ((size_t)b * S_ + s0) * H_ + h;
    float* Yb = Y + ((size_t)b * S_ + s0) * H_ + h;
    float c = (s0 == 0) ? 0.f : carry[gid];

    float Af[8], Ac[8], Ar[8], Ax[8];
    float Bf[8], Bc[8], Br[8], Bx[8];
    float Cg[8], Cc[8], Cr[8], Cx[8];
    float Df[8], Dc[8], Dr[8], Dx[8];

    auto LOAD = [&](int t0, float (&sf)[8], float (&sc)[8], float (&sr)[8], float (&sx)[8]) {
#pragma unroll
        for (int u = 0; u < 8; ++u) {
            size_t o = (size_t)(t0 + u) * K3_;
            sf[u] = Ub[o];
            sc[u] = Ub[o + H_];
            sr[u] = Ub[o + 2 * H_];
            sx[u] = Xb[(size_t)(t0 + u) * H_];
        }
    };
    auto COMP = [&](int t0, float (&sf)[8], float (&sc)[8], float (&sr)[8], float (&sx)[8]) {
#pragma unroll
        for (int u = 0; u < 8; ++u) {
            float zf = sf[u] + bfh + vfh * c;
            float zr = sr[u] + brh + vrh * c;
            float xc = sc[u];
            float ft = __builtin_amdgcn_rcpf(1.f + __expf(-zf));
            float rt = __builtin_amdgcn_rcpf(1.f + __expf(-zr));
            c = ft * (c - xc) + xc;
            float xv = sx[u];
            float ht = rt * (c - xv) + xv;
            Yb[(size_t)(t0 + u) * H_] = ht;
        }
    };

    LOAD(0, Af, Ac, Ar, Ax);
    LOAD(8, Bf, Bc, Br, Bx);
    LOAD(16, Cg, Cc, Cr, Cx);
    for (int t0 = 0; t0 < SC_; t0 += 32) {
        LOAD(t0 + 24, Df, Dc, Dr, Dx);            // t0+24 <= 504 always in range
        COMP(t0, Af, Ac, Ar, Ax);
        if (t0 + 32 < SC_) LOAD(t0 + 32, Af, Ac, Ar, Ax);
        COMP(t0 + 8, Bf, Bc, Br, Bx);
        if (t0 + 40 < SC_) LOAD(t0 + 40, Bf, Bc, Br, Bx);
        COMP(t0 + 16, Cg, Cc, Cr, Cx);
        if (t0 + 48 < SC_) LOAD(t0 + 48, Cg, Cc, Cr, Cx);
        COMP(t0 + 24, Df, Dc, Dr, Dx);
    }
    carry[gid] = c;
    if (last) Cf[(size_t)b * H_ + h] = c;
}

// ---------------------------------------------------------------- launcher
extern "C" void kernel_launch(void* const* d_in, const int* in_sizes, int n_in,
                              void* d_out, int out_size, void* d_ws, size_t ws_size,
                              hipStream_t stream) {
    const float* x  = (const float*)d_in[0];
    const float* W  = (const float*)d_in[1];
    const float* vf = (const float*)d_in[2];
    const float* vr = (const float*)d_in[3];
    const float* bf = (const float*)d_in[4];
    const float* br = (const float*)d_in[5];
    float* y  = (float*)d_out;
    float* cf = y + (size_t)B_ * S_ * H_;

    // ws layout: U_c fp32 50.3MB | xh 8.4MB | xl 8.4MB | Wth 6.3MB | Wtl 6.3MB | carry 32KB  => ~79.8MB
    float* U = (float*)d_ws;
    _Float16* xh  = (_Float16*)(U + (size_t)MC_ * K3_);
    _Float16* xl  = xh + (size_t)MC_ * H_;
    _Float16* Wth = xl + (size_t)MC_ * H_;
    _Float16* Wtl = Wth + (size_t)K3_ * H_;
    float* carry  = (float*)(Wtl + (size_t)K3_ * H_);

    transW_kernel<<<dim3(K3_ / 32, H_ / 32), 256, 0, stream>>>(W, Wth, Wtl);
    for (int ci = 0; ci < NCH_; ++ci) {
        int s0 = ci * SC_;
        castx_kernel<<<(MC_ * H_ / 4) / 256, 256, 0, stream>>>((const float4*)x, (f16x4*)xh, (f16x4*)xl, s0);
        gemm_kernel<<<dim3(K3_ / 128, MC_ / 128), 256, 0, stream>>>(xh, xl, Wth, Wtl, U);
        scan_kernel<<<(B_ * H_) / 64, 64, 0, stream>>>(U, x, vf, vr, bf, br, y, cf, carry,
                                                       s0, ci == NCH_ - 1 ? 1 : 0);
    }
}